// Round 23
// baseline (181.500 us; speedup 1.0000x reference)
//
#include <hip/hip_runtime.h>
#include <hip/hip_bf16.h>
#include <math.h>

#define M_TOT   16384      // B*N = 4*4096
#define F_DIM   768
#define C_DIM   64
#define P_DIM   8192
#define EPSN    1e-12f
#define NEG_BIG (-3.402823466e38f)
#define NCH     16
#define PCH     (P_DIM / NCH)   // 512
#define GRP     32
#define NGRP    (P_DIM / GRP)   // 256
#define MARG    1e-2f           // >= 2 * 4e-3 hard bf16x1 screen error bound

typedef __attribute__((ext_vector_type(8))) short bf16x8;
typedef __attribute__((ext_vector_type(4))) float f32x4;
typedef __attribute__((ext_vector_type(16))) float f32x16;
typedef unsigned short ushort_t;
typedef const __attribute__((address_space(1))) void* gas1_t;
typedef __attribute__((address_space(3))) void* las3_t;

__device__ inline ushort_t bf16hi(float v) {
    __hip_bfloat16 hb = __float2bfloat16(v);
    return *reinterpret_cast<ushort_t*>(&hb);
}

// MFMA-fragment-order layout (r20, proven):
//   frag tile g = row>>5 occupies chF[g*2048 .. +2048): contiguous.
//   offset within tile: fi*256 + (row&31)*8 + (k&7), fi = (k>>4)*2 + ((k>>3)&1)
__device__ inline size_t fragAddr(int row, int k) {
    return ((size_t)(row >> 5) * 8 + (k >> 4) * 2 + ((k >> 3) & 1)) * 256
         + (row & 31) * 8 + (k & 7);
}

// Pick-ordered fp32 codebook copy (r22, proven): group tile g contiguous:
//   cnG[g*2048 + (k&31)*64 + (k>>5)*32 + (code&31)]
__device__ inline size_t pickAddr(int row, int k) {
    return (size_t)(row >> 5) * 2048 + (k & 31) * 64 + (k >> 5) * 32 + (row & 31);
}

// ---------------- Kernel B (merged with prep): proj + cb-norm + wout-T ----------
// blocks [0,512): proj tile (bitwise-identical zn chain).
// blocks [512,768): one 32-code group each: xor-tree norm (bitwise-identical cn),
//   LDS stage, then chF (4KB) + cnG (8KB) written as CONTIGUOUS slices.
// blocks [768,780): 64f x 64c LDS-transpose tiles of w_out -> wT (coalesced both sides).
#define PBM 32
#define PKC 64
#define PROJ_BLKS (M_TOT / PBM)             // 512
__global__ __launch_bounds__(256)
void k_proj(const float* __restrict__ z, const float* __restrict__ w_in,
            float* __restrict__ zn, ushort_t* __restrict__ zhF,
            const float* __restrict__ cb, float* __restrict__ cn,
            ushort_t* __restrict__ chF, float* __restrict__ cnG,
            const float* __restrict__ w_out, float* __restrict__ wT) {
    __shared__ float lw[2][C_DIM * PKC];   // 32 KB; prep branches overlay this

    const int bx = blockIdx.x;
    if (bx >= PROJ_BLKS) {
        int pb = bx - PROJ_BLKS;
        float* lsc = (float*)lw;            // staging overlay
        if (pb < NGRP) {                    // --- codebook group pb (32 rows) ---
            int wv = threadIdx.x >> 6, lane = threadIdx.x & 63;
            #pragma unroll
            for (int i = 0; i < 8; ++i) {
                int r31 = wv * 8 + i;
                int row = pb * 32 + r31;
                float v = cb[(size_t)row * C_DIM + lane];
                float s = v * v;
                #pragma unroll
                for (int o = 32; o; o >>= 1) s += __shfl_xor(s, o, 64);
                float inv = 1.0f / fmaxf(sqrtf(s), EPSN);
                float nv = v * inv;             // BITWISE same cn as r22
                cn[(size_t)row * C_DIM + lane] = nv;
                lsc[r31 * 65 + lane] = nv;
            }
            __syncthreads();
            int t = threadIdx.x;
            {   // chF: thread t writes 8 contiguous ushorts at tile offset t*8
                int st = (t >> 6) & 3, kh = (t >> 5) & 1, r31 = t & 31;
                int kb = st * 16 + kh * 8;
                ushort_t tmp[8];
                #pragma unroll
                for (int e = 0; e < 8; ++e)
                    tmp[e] = bf16hi(lsc[r31 * 65 + kb + e]);
                ushort_t* d = chF + (size_t)pb * 2048 + t * 8;
                *(ushort4*)(d)     = *(ushort4*)&tmp[0];
                *(ushort4*)(d + 4) = *(ushort4*)&tmp[4];
            }
            {   // cnG: thread t writes 8 contiguous floats at tile offset t*8
                int j = t >> 3, h = (t >> 2) & 1;
                int k = h * 32 + j;
                float tmp[8];
                #pragma unroll
                for (int e = 0; e < 8; ++e)
                    tmp[e] = lsc[((t & 3) * 8 + e) * 65 + k];
                float* d = cnG + (size_t)pb * 2048 + t * 8;
                *(float4*)(d)     = *(float4*)&tmp[0];
                *(float4*)(d + 4) = *(float4*)&tmp[4];
            }
        } else {                            // --- wT transpose tile (64f x 64c) ---
            int tb = pb - NGRP;             // 0..11
            int t = threadIdx.x;
            #pragma unroll
            for (int i = 0; i < 16; ++i) {  // coalesced read w_out
                int e = i * 256 + t;
                int fl = e >> 6, c = e & 63;
                lsc[c * 65 + fl] = w_out[(size_t)(tb * 64 + fl) * C_DIM + c];
            }
            __syncthreads();
            #pragma unroll
            for (int i = 0; i < 16; ++i) {  // coalesced write wT
                int e = i * 256 + t;
                int c = e >> 6, fl = e & 63;
                wT[(size_t)c * F_DIM + tb * 64 + fl] = lsc[c * 65 + fl];
            }
        }
        return;
    }

    const int t  = threadIdx.x;
    const int m0 = bx * PBM;
    const int r0 = (t >> 4) * 2;        // rows r0..r0+1  (t>>4 in 0..15)
    const int c0 = (t & 15) * 4;        // cols c0..c0+3
    const int wswz = t & 15;            // == ((c0+cj)>>2)&15 for cj<4

    const float* zrow[2];
    #pragma unroll
    for (int ri = 0; ri < 2; ++ri)
        zrow[ri] = z + (size_t)(m0 + r0 + ri) * F_DIM;

    float acc[2][4];
    #pragma unroll
    for (int i = 0; i < 2; ++i)
        #pragma unroll
        for (int j = 0; j < 4; ++j) acc[i][j] = 0.0f;

    // stage w chunk 0 into buffer 0 (1024 float4 over 256 thr = 4 each)
    #pragma unroll
    for (int i = 0; i < 4; ++i) {
        int f4 = i * 256 + t; int c = f4 >> 4, s4 = f4 & 15;
        __builtin_amdgcn_global_load_lds(
            (gas1_t)(w_in + (size_t)c * F_DIM + (s4 ^ ((c >> 2) & 15)) * 4),
            (las3_t)(&lw[0][f4 * 4]), 16, 0, 0);
    }
    __syncthreads();

    int cur = 0;
    for (int k0 = 0; k0 < F_DIM; k0 += PKC) {       // 12 chunks
        if (k0 + PKC < F_DIM) {                     // issue next-chunk DMA first
            int nxt = cur ^ 1;
            #pragma unroll
            for (int i = 0; i < 4; ++i) {
                int f4 = i * 256 + t; int c = f4 >> 4, s4 = f4 & 15;
                __builtin_amdgcn_global_load_lds(
                    (gas1_t)(w_in + (size_t)c * F_DIM + k0 + PKC
                             + (s4 ^ ((c >> 2) & 15)) * 4),
                    (las3_t)(&lw[nxt][f4 * 4]), 16, 0, 0);
            }
        }

        const float* lwb = lw[cur];
        #pragma unroll
        for (int kq = 0; kq < 16; ++kq) {
            float4 zf[2], wf[4];
            int wo = (kq ^ wswz) * 4;
            #pragma unroll
            for (int ri = 0; ri < 2; ++ri)
                zf[ri] = *(const float4*)(zrow[ri] + k0 + kq * 4);
            #pragma unroll
            for (int cj = 0; cj < 4; ++cj)
                wf[cj] = *(const float4*)(lwb + (c0 + cj) * PKC + wo);
            #pragma unroll
            for (int ri = 0; ri < 2; ++ri)
                #pragma unroll
                for (int cj = 0; cj < 4; ++cj) {
                    acc[ri][cj] = fmaf(zf[ri].x, wf[cj].x, acc[ri][cj]);
                    acc[ri][cj] = fmaf(zf[ri].y, wf[cj].y, acc[ri][cj]);
                    acc[ri][cj] = fmaf(zf[ri].z, wf[cj].z, acc[ri][cj]);
                    acc[ri][cj] = fmaf(zf[ri].w, wf[cj].w, acc[ri][cj]);
                }
        }
        __syncthreads();    // vmcnt(0)+barrier: next w chunk landed, cur free
        cur ^= 1;
    }

    // ---- epilogue: row-norm; zn bitwise-identical, zh scattered to frag order
    #pragma unroll
    for (int ri = 0; ri < 2; ++ri) {
        float s = acc[ri][0] * acc[ri][0] + acc[ri][1] * acc[ri][1]
                + acc[ri][2] * acc[ri][2] + acc[ri][3] * acc[ri][3];
        #pragma unroll
        for (int o = 1; o < 16; o <<= 1) s += __shfl_xor(s, o, 64);
        float inv = 1.0f / fmaxf(sqrtf(s), EPSN);
        float4 v;
        v.x = acc[ri][0] * inv; v.y = acc[ri][1] * inv;
        v.z = acc[ri][2] * inv; v.w = acc[ri][3] * inv;
        int m = m0 + r0 + ri;
        *(float4*)(zn + (size_t)m * C_DIM + c0) = v;
        ushort4 hv = {bf16hi(v.x), bf16hi(v.y), bf16hi(v.z), bf16hi(v.w)};
        *(ushort4*)(zhF + fragAddr(m, c0)) = hv;
    }
}

// ---------------- Kernel C: bf16x1 32x32x16-MFMA screen, coalesced frag loads ----
// r21's proven version: gmaxT[M_TOT][NGRP], per-lane register accumulation.
__global__ __launch_bounds__(256, 4)
void k_simmax(const ushort_t* __restrict__ zhF, const ushort_t* __restrict__ chF,
              float* __restrict__ gmaxT) {
    int wv = threadIdx.x >> 6, l = threadIdx.x & 63;
    int m0 = (blockIdx.x * 4 + wv) * 64;
    int p0 = blockIdx.y * PCH;

    bf16x8 bh[2][4];
    #pragma unroll
    for (int mt = 0; mt < 2; ++mt) {
        const ushort_t* zb = zhF + ((size_t)(m0 >> 5) + mt) * 2048;
        #pragma unroll
        for (int st = 0; st < 4; ++st)
            bh[mt][st] = *(const bf16x8*)(zb + st * 512 + l * 8);
    }

    float sel[16];      // per-lane row (m0+l) group maxima for this chunk

    #pragma unroll
    for (int g = 0; g < PCH / GRP; ++g) {           // 16 groups of 32 p
        const ushort_t* ab = chF + ((size_t)(p0 >> 5) + g) * 2048;
        bf16x8 a0 = *(const bf16x8*)(ab + 0 * 512 + l * 8);
        bf16x8 a1 = *(const bf16x8*)(ab + 1 * 512 + l * 8);
        bf16x8 a2 = *(const bf16x8*)(ab + 2 * 512 + l * 8);
        bf16x8 a3 = *(const bf16x8*)(ab + 3 * 512 + l * 8);

        float gm[2];
        #pragma unroll
        for (int mt = 0; mt < 2; ++mt) {
            f32x16 acc = {0.f, 0.f, 0.f, 0.f, 0.f, 0.f, 0.f, 0.f,
                          0.f, 0.f, 0.f, 0.f, 0.f, 0.f, 0.f, 0.f};
            acc = __builtin_amdgcn_mfma_f32_32x32x16_bf16(a0, bh[mt][0], acc, 0, 0, 0);
            acc = __builtin_amdgcn_mfma_f32_32x32x16_bf16(a1, bh[mt][1], acc, 0, 0, 0);
            acc = __builtin_amdgcn_mfma_f32_32x32x16_bf16(a2, bh[mt][2], acc, 0, 0, 0);
            acc = __builtin_amdgcn_mfma_f32_32x32x16_bf16(a3, bh[mt][3], acc, 0, 0, 0);
            float v0 = fmaxf(acc[0], acc[1]),   v1 = fmaxf(acc[2], acc[3]);
            float v2 = fmaxf(acc[4], acc[5]),   v3 = fmaxf(acc[6], acc[7]);
            float v4 = fmaxf(acc[8], acc[9]),   v5 = fmaxf(acc[10], acc[11]);
            float v6 = fmaxf(acc[12], acc[13]), v7 = fmaxf(acc[14], acc[15]);
            float v = fmaxf(fmaxf(fmaxf(v0, v1), fmaxf(v2, v3)),
                            fmaxf(fmaxf(v4, v5), fmaxf(v6, v7)));
            gm[mt] = fmaxf(v, __shfl_xor(v, 32, 64));   // both halves hold max
        }
        sel[g] = (l < 32) ? gm[0] : gm[1];  // lane l owns row m0 + l
    }

    float* dst = gmaxT + (size_t)(m0 + l) * NGRP + blockIdx.y * (PCH / GRP);
    #pragma unroll
    for (int q = 0; q < 4; ++q) {
        float4 st = {sel[4 * q], sel[4 * q + 1], sel[4 * q + 2], sel[4 * q + 3]};
        *(float4*)(dst + 4 * q) = st;
    }
}

// ---------------- Kernel C2: per-row pick + fused loss partial ----------
// r22's proven version: coalesced gmaxT + cnG reads, exact fp32 rescan.
__global__ __launch_bounds__(256)
void k_pick(const float* __restrict__ gmaxT, const float* __restrict__ zn,
            const float* __restrict__ cn, const float* __restrict__ cnG,
            int* __restrict__ idx_i, float* __restrict__ idx_f,
            float* __restrict__ lossp) {
    int wv = threadIdx.x >> 6, l = threadIdx.x & 63;
    int m = blockIdx.x * 4 + wv;            // one wave per row

    float gv[4];
    #pragma unroll
    for (int b = 0; b < 4; ++b)
        gv[b] = gmaxT[(size_t)m * NGRP + b * 64 + l];
    float rm = fmaxf(fmaxf(gv[0], gv[1]), fmaxf(gv[2], gv[3]));
    #pragma unroll
    for (int o = 32; o; o >>= 1) rm = fmaxf(rm, __shfl_xor(rm, o, 64));
    float thr = rm - MARG;

    float zr[32];
    {
        const float4* zp = (const float4*)(zn + (size_t)m * C_DIM + (l >> 5) * 32);
        #pragma unroll
        for (int q = 0; q < 8; ++q) {
            float4 v = zp[q];
            zr[4 * q] = v.x; zr[4 * q + 1] = v.y;
            zr[4 * q + 2] = v.z; zr[4 * q + 3] = v.w;
        }
    }

    float bv = NEG_BIG; int bp = P_DIM;
    #pragma unroll
    for (int b = 0; b < 4; ++b) {           // ascending batches -> ascending groups
        unsigned long long mask = __ballot(gv[b] >= thr);
        while (mask) {
            int j = __ffsll((unsigned long long)mask) - 1;
            mask &= mask - 1;               // ascending j within batch
            int g = b * 64 + j;
            int p = g * GRP + (l & 31);
            const float* cg = cnG + (size_t)g * 2048;
            float a0 = 0.f, a1 = 0.f, a2 = 0.f, a3 = 0.f;
            #pragma unroll
            for (int q = 0; q < 8; ++q) {
                a0 = fmaf(cg[(4 * q + 0) * 64 + l], zr[4 * q + 0], a0);
                a1 = fmaf(cg[(4 * q + 1) * 64 + l], zr[4 * q + 1], a1);
                a2 = fmaf(cg[(4 * q + 2) * 64 + l], zr[4 * q + 2], a2);
                a3 = fmaf(cg[(4 * q + 3) * 64 + l], zr[4 * q + 3], a3);
            }
            float s = (a0 + a1) + (a2 + a3);
            s += __shfl_xor(s, 32, 64);     // combine halves: full dot in both lanes
            if (s > bv || (s == bv && p < bp)) { bv = s; bp = p; }
        }
    }
    #pragma unroll
    for (int o = 32; o; o >>= 1) {
        float ov = __shfl_xor(bv, o, 64);
        int   op = __shfl_xor(bp, o, 64);
        if (ov > bv || (ov == bv && op < bp)) { bv = ov; bp = op; }
    }
    if (l == 0) { idx_i[m] = bp; idx_f[m] = (float)bp; }

    // fused loss partial: sum (zn - cn[bp])^2 over the row (bp wave-uniform)
    {
        const float4* cp = (const float4*)(cn + (size_t)bp * C_DIM + (l >> 5) * 32);
        float d2 = 0.f;
        #pragma unroll
        for (int q = 0; q < 8; ++q) {
            float4 w = cp[q];
            float dx = zr[4 * q + 0] - w.x; d2 = fmaf(dx, dx, d2);
            float dy = zr[4 * q + 1] - w.y; d2 = fmaf(dy, dy, d2);
            float dz = zr[4 * q + 2] - w.z; d2 = fmaf(dz, dz, d2);
            float dw = zr[4 * q + 3] - w.w; d2 = fmaf(dw, dw, d2);
        }
        d2 += __shfl_xor(d2, 32, 64);
        if (l == 0) lossp[m] = d2;
    }
}

// ---------------- Kernel D (merged with loss-final): out + loss reduce ----------
// idx preloaded coalesced (32 lanes) + shfl broadcast per row.
#define D_ROWS 128
#define D_BLKS (M_TOT / D_ROWS * (F_DIM / 64))      // 1536
__global__ void k_out(const int* __restrict__ idx, const float* __restrict__ cn,
                      const float* __restrict__ wT, float* __restrict__ out,
                      const float* __restrict__ lossp, float* __restrict__ loss_out) {
    __shared__ float sh[256];
    int bx = blockIdx.x;
    if (bx >= D_BLKS) {
        float s = 0.f;
        for (int i = threadIdx.x; i < M_TOT; i += 256) s += lossp[i];
        sh[threadIdx.x] = s;
        __syncthreads();
        for (int o = 128; o; o >>= 1) {
            if (threadIdx.x < o) sh[threadIdx.x] += sh[threadIdx.x + o];
            __syncthreads();
        }
        if (threadIdx.x == 0)
            loss_out[0] = 1.25f * sh[0] / (float)(M_TOT * C_DIM);
        return;
    }

    int wv = threadIdx.x >> 6, lane = threadIdx.x & 63;
    int f  = (bx >> 7) * 64 + lane;     // bx/128 in 0..11
    int m0 = (bx & 127) * D_ROWS + wv * 32;

    int iv = (lane < 32) ? idx[m0 + lane] : 0;      // coalesced idx preload

    float wcol[64];
    #pragma unroll
    for (int c = 0; c < 64; ++c) wcol[c] = wT[(size_t)c * F_DIM + f];

    #pragma unroll 4
    for (int r = 0; r < 32; ++r) {
        int ci = __shfl(iv, r, 64);     // wave-uniform code index for row r
        const float4* cp = (const float4*)(cn + (size_t)ci * C_DIM);
        float a0 = 0.f, a1 = 0.f, a2 = 0.f, a3 = 0.f;
        #pragma unroll
        for (int j = 0; j < 16; ++j) {
            float4 cv = cp[j];
            a0 = fmaf(cv.x, wcol[4 * j + 0], a0);
            a1 = fmaf(cv.y, wcol[4 * j + 1], a1);
            a2 = fmaf(cv.z, wcol[4 * j + 2], a2);
            a3 = fmaf(cv.w, wcol[4 * j + 3], a3);
        }
        out[(size_t)(m0 + r) * F_DIM + f] = (a0 + a1) + (a2 + a3);
    }
}

extern "C" void kernel_launch(void* const* d_in, const int* in_sizes, int n_in,
                              void* d_out, int out_size, void* d_ws, size_t ws_size,
                              hipStream_t stream) {
    const float* z     = (const float*)d_in[0];
    const float* w_in  = (const float*)d_in[1];
    const float* w_out = (const float*)d_in[2];
    const float* cb    = (const float*)d_in[3];

    float* out    = (float*)d_out;
    float* lossO  = out + (size_t)M_TOT * F_DIM;
    float* idxO   = lossO + 1;
    // gmaxT (16.8 MB, [M_TOT][NGRP]) lives in the d_out 'out' region: written by
    // k_simmax, read by k_pick, then fully overwritten by k_out (stream-ordered).
    float* gmaxT  = out;

    float* ws    = (float*)d_ws;                          // total ~11.4 MB
    float* cn    = ws;                                    // 524288 f   (2 MB)
    float* zn    = cn + (size_t)P_DIM * C_DIM;            // 1048576 f  (4 MB)
    float* wT    = zn + (size_t)M_TOT * C_DIM;            // 49152 f
    float* lossp = wT + (size_t)C_DIM * F_DIM;            // 16384 f
    int*   idxi  = (int*)(lossp + M_TOT);                 // 16384 i
    float* cnG   = (float*)(idxi + M_TOT);                // 524288 f   (2 MB)
    ushort_t* zhF = (ushort_t*)(cnG + (size_t)P_DIM * C_DIM); // 1048576 us (2 MB)
    ushort_t* chF = zhF + (size_t)M_TOT * C_DIM;          // 524288 us  (1 MB)

    int projGrid = PROJ_BLKS + NGRP + F_DIM / 64;         // 512 + 256 + 12
    k_proj<<<projGrid, 256, 0, stream>>>(z, w_in, zn, zhF, cb, cn, chF, cnG, w_out, wT);

    dim3 gC(M_TOT / 256, NCH);
    k_simmax<<<gC, 256, 0, stream>>>(zhF, chF, gmaxT);
    k_pick<<<M_TOT / 4, 256, 0, stream>>>(gmaxT, zn, cn, cnG, idxi, idxO, lossp);

    k_out<<<D_BLKS + 1, 256, 0, stream>>>(idxi, cn, wT, out, lossp, lossO);
}

// Round 24
// 128.326 us; speedup vs baseline: 1.4144x; 1.4144x over previous
//
#include <hip/hip_runtime.h>
#include <hip/hip_bf16.h>
#include <math.h>

#define M_TOT   16384      // B*N = 4*4096
#define F_DIM   768
#define C_DIM   64
#define P_DIM   8192
#define EPSN    1e-12f
#define NEG_BIG (-3.402823466e38f)
#define NCH     16
#define PCH     (P_DIM / NCH)   // 512
#define GRP     32
#define NGRP    (P_DIM / GRP)   // 256
#define MARG    1e-2f           // >= 2 * 4e-3 hard bf16x1 screen error bound

typedef __attribute__((ext_vector_type(8))) short bf16x8;
typedef __attribute__((ext_vector_type(4))) float f32x4;
typedef __attribute__((ext_vector_type(16))) float f32x16;
typedef unsigned short ushort_t;
typedef const __attribute__((address_space(1))) void* gas1_t;
typedef __attribute__((address_space(3))) void* las3_t;

__device__ inline ushort_t bf16hi(float v) {
    __hip_bfloat16 hb = __float2bfloat16(v);
    return *reinterpret_cast<ushort_t*>(&hb);
}

// MFMA-fragment-order layout (r20, proven):
//   frag tile g = row>>5 occupies chF[g*2048 .. +2048): contiguous.
__device__ inline size_t fragAddr(int row, int k) {
    return ((size_t)(row >> 5) * 8 + (k >> 4) * 2 + ((k >> 3) & 1)) * 256
         + (row & 31) * 8 + (k & 7);
}

// Pick-ordered fp32 codebook copy (r22, proven): group tile g contiguous:
//   cnG[g*2048 + (k&31)*64 + (k>>5)*32 + (code&31)]
__device__ inline size_t pickAddr(int row, int k) {
    return (size_t)(row >> 5) * 2048 + (k & 31) * 64 + (k >> 5) * 32 + (row & 31);
}

// ---------------- Kernel B (merged with prep): proj + cb-norm + wout-T ----------
// blocks [0,512): proj tile (bitwise-identical zn chain).
// blocks [512,768): one 32-code group each: xor-tree norm (bitwise-identical cn),
//   LDS stage, then chF (4KB) + cnG (8KB) written as CONTIGUOUS slices.
// blocks [768,780): 64f x 64c LDS-transpose tiles of w_out -> wT.
#define PBM 32
#define PKC 64
#define PROJ_BLKS (M_TOT / PBM)             // 512
__global__ __launch_bounds__(256)
void k_proj(const float* __restrict__ z, const float* __restrict__ w_in,
            float* __restrict__ zn, ushort_t* __restrict__ zhF,
            const float* __restrict__ cb, float* __restrict__ cn,
            ushort_t* __restrict__ chF, float* __restrict__ cnG,
            const float* __restrict__ w_out, float* __restrict__ wT) {
    __shared__ float lw[2][C_DIM * PKC];   // 32 KB; prep branches overlay this

    const int bx = blockIdx.x;
    if (bx >= PROJ_BLKS) {
        int pb = bx - PROJ_BLKS;
        float* lsc = (float*)lw;            // staging overlay
        if (pb < NGRP) {                    // --- codebook group pb (32 rows) ---
            int wv = threadIdx.x >> 6, lane = threadIdx.x & 63;
            #pragma unroll
            for (int i = 0; i < 8; ++i) {
                int r31 = wv * 8 + i;
                int row = pb * 32 + r31;
                float v = cb[(size_t)row * C_DIM + lane];
                float s = v * v;
                #pragma unroll
                for (int o = 32; o; o >>= 1) s += __shfl_xor(s, o, 64);
                float inv = 1.0f / fmaxf(sqrtf(s), EPSN);
                float nv = v * inv;             // BITWISE same cn as r22
                cn[(size_t)row * C_DIM + lane] = nv;
                lsc[r31 * 65 + lane] = nv;
            }
            __syncthreads();
            int t = threadIdx.x;
            {   // chF: thread t writes 8 contiguous ushorts at tile offset t*8
                int st = (t >> 6) & 3, kh = (t >> 5) & 1, r31 = t & 31;
                int kb = st * 16 + kh * 8;
                ushort_t tmp[8];
                #pragma unroll
                for (int e = 0; e < 8; ++e)
                    tmp[e] = bf16hi(lsc[r31 * 65 + kb + e]);
                ushort_t* d = chF + (size_t)pb * 2048 + t * 8;
                *(ushort4*)(d)     = *(ushort4*)&tmp[0];
                *(ushort4*)(d + 4) = *(ushort4*)&tmp[4];
            }
            {   // cnG: thread t writes 8 contiguous floats at tile offset t*8
                int j = t >> 3, h = (t >> 2) & 1;
                int k = h * 32 + j;
                float tmp[8];
                #pragma unroll
                for (int e = 0; e < 8; ++e)
                    tmp[e] = lsc[((t & 3) * 8 + e) * 65 + k];
                float* d = cnG + (size_t)pb * 2048 + t * 8;
                *(float4*)(d)     = *(float4*)&tmp[0];
                *(float4*)(d + 4) = *(float4*)&tmp[4];
            }
        } else {                            // --- wT transpose tile (64f x 64c) ---
            int tb = pb - NGRP;             // 0..11
            int t = threadIdx.x;
            #pragma unroll
            for (int i = 0; i < 16; ++i) {  // coalesced read w_out
                int e = i * 256 + t;
                int fl = e >> 6, c = e & 63;
                lsc[c * 65 + fl] = w_out[(size_t)(tb * 64 + fl) * C_DIM + c];
            }
            __syncthreads();
            #pragma unroll
            for (int i = 0; i < 16; ++i) {  // coalesced write wT
                int e = i * 256 + t;
                int c = e >> 6, fl = e & 63;
                wT[(size_t)c * F_DIM + tb * 64 + fl] = lsc[c * 65 + fl];
            }
        }
        return;
    }

    const int t  = threadIdx.x;
    const int m0 = bx * PBM;
    const int r0 = (t >> 4) * 2;        // rows r0..r0+1  (t>>4 in 0..15)
    const int c0 = (t & 15) * 4;        // cols c0..c0+3
    const int wswz = t & 15;            // == ((c0+cj)>>2)&15 for cj<4

    const float* zrow[2];
    #pragma unroll
    for (int ri = 0; ri < 2; ++ri)
        zrow[ri] = z + (size_t)(m0 + r0 + ri) * F_DIM;

    float acc[2][4];
    #pragma unroll
    for (int i = 0; i < 2; ++i)
        #pragma unroll
        for (int j = 0; j < 4; ++j) acc[i][j] = 0.0f;

    // stage w chunk 0 into buffer 0 (1024 float4 over 256 thr = 4 each)
    #pragma unroll
    for (int i = 0; i < 4; ++i) {
        int f4 = i * 256 + t; int c = f4 >> 4, s4 = f4 & 15;
        __builtin_amdgcn_global_load_lds(
            (gas1_t)(w_in + (size_t)c * F_DIM + (s4 ^ ((c >> 2) & 15)) * 4),
            (las3_t)(&lw[0][f4 * 4]), 16, 0, 0);
    }
    __syncthreads();

    int cur = 0;
    for (int k0 = 0; k0 < F_DIM; k0 += PKC) {       // 12 chunks
        if (k0 + PKC < F_DIM) {                     // issue next-chunk DMA first
            int nxt = cur ^ 1;
            #pragma unroll
            for (int i = 0; i < 4; ++i) {
                int f4 = i * 256 + t; int c = f4 >> 4, s4 = f4 & 15;
                __builtin_amdgcn_global_load_lds(
                    (gas1_t)(w_in + (size_t)c * F_DIM + k0 + PKC
                             + (s4 ^ ((c >> 2) & 15)) * 4),
                    (las3_t)(&lw[nxt][f4 * 4]), 16, 0, 0);
            }
        }

        const float* lwb = lw[cur];
        #pragma unroll
        for (int kq = 0; kq < 16; ++kq) {
            float4 zf[2], wf[4];
            int wo = (kq ^ wswz) * 4;
            #pragma unroll
            for (int ri = 0; ri < 2; ++ri)
                zf[ri] = *(const float4*)(zrow[ri] + k0 + kq * 4);
            #pragma unroll
            for (int cj = 0; cj < 4; ++cj)
                wf[cj] = *(const float4*)(lwb + (c0 + cj) * PKC + wo);
            #pragma unroll
            for (int ri = 0; ri < 2; ++ri)
                #pragma unroll
                for (int cj = 0; cj < 4; ++cj) {
                    acc[ri][cj] = fmaf(zf[ri].x, wf[cj].x, acc[ri][cj]);
                    acc[ri][cj] = fmaf(zf[ri].y, wf[cj].y, acc[ri][cj]);
                    acc[ri][cj] = fmaf(zf[ri].z, wf[cj].z, acc[ri][cj]);
                    acc[ri][cj] = fmaf(zf[ri].w, wf[cj].w, acc[ri][cj]);
                }
        }
        __syncthreads();    // vmcnt(0)+barrier: next w chunk landed, cur free
        cur ^= 1;
    }

    // ---- epilogue: row-norm; zn bitwise-identical, zh scattered to frag order
    #pragma unroll
    for (int ri = 0; ri < 2; ++ri) {
        float s = acc[ri][0] * acc[ri][0] + acc[ri][1] * acc[ri][1]
                + acc[ri][2] * acc[ri][2] + acc[ri][3] * acc[ri][3];
        #pragma unroll
        for (int o = 1; o < 16; o <<= 1) s += __shfl_xor(s, o, 64);
        float inv = 1.0f / fmaxf(sqrtf(s), EPSN);
        float4 v;
        v.x = acc[ri][0] * inv; v.y = acc[ri][1] * inv;
        v.z = acc[ri][2] * inv; v.w = acc[ri][3] * inv;
        int m = m0 + r0 + ri;
        *(float4*)(zn + (size_t)m * C_DIM + c0) = v;
        ushort4 hv = {bf16hi(v.x), bf16hi(v.y), bf16hi(v.z), bf16hi(v.w)};
        *(ushort4*)(zhF + fragAddr(m, c0)) = hv;
    }
}

// ---------------- Kernel C: bf16x1 32x32x16-MFMA screen, coalesced frag loads ----
__global__ __launch_bounds__(256, 4)
void k_simmax(const ushort_t* __restrict__ zhF, const ushort_t* __restrict__ chF,
              float* __restrict__ gmaxT) {
    int wv = threadIdx.x >> 6, l = threadIdx.x & 63;
    int m0 = (blockIdx.x * 4 + wv) * 64;
    int p0 = blockIdx.y * PCH;

    bf16x8 bh[2][4];
    #pragma unroll
    for (int mt = 0; mt < 2; ++mt) {
        const ushort_t* zb = zhF + ((size_t)(m0 >> 5) + mt) * 2048;
        #pragma unroll
        for (int st = 0; st < 4; ++st)
            bh[mt][st] = *(const bf16x8*)(zb + st * 512 + l * 8);
    }

    float sel[16];      // per-lane row (m0+l) group maxima for this chunk

    #pragma unroll
    for (int g = 0; g < PCH / GRP; ++g) {           // 16 groups of 32 p
        const ushort_t* ab = chF + ((size_t)(p0 >> 5) + g) * 2048;
        bf16x8 a0 = *(const bf16x8*)(ab + 0 * 512 + l * 8);
        bf16x8 a1 = *(const bf16x8*)(ab + 1 * 512 + l * 8);
        bf16x8 a2 = *(const bf16x8*)(ab + 2 * 512 + l * 8);
        bf16x8 a3 = *(const bf16x8*)(ab + 3 * 512 + l * 8);

        float gm[2];
        #pragma unroll
        for (int mt = 0; mt < 2; ++mt) {
            f32x16 acc = {0.f, 0.f, 0.f, 0.f, 0.f, 0.f, 0.f, 0.f,
                          0.f, 0.f, 0.f, 0.f, 0.f, 0.f, 0.f, 0.f};
            acc = __builtin_amdgcn_mfma_f32_32x32x16_bf16(a0, bh[mt][0], acc, 0, 0, 0);
            acc = __builtin_amdgcn_mfma_f32_32x32x16_bf16(a1, bh[mt][1], acc, 0, 0, 0);
            acc = __builtin_amdgcn_mfma_f32_32x32x16_bf16(a2, bh[mt][2], acc, 0, 0, 0);
            acc = __builtin_amdgcn_mfma_f32_32x32x16_bf16(a3, bh[mt][3], acc, 0, 0, 0);
            float v0 = fmaxf(acc[0], acc[1]),   v1 = fmaxf(acc[2], acc[3]);
            float v2 = fmaxf(acc[4], acc[5]),   v3 = fmaxf(acc[6], acc[7]);
            float v4 = fmaxf(acc[8], acc[9]),   v5 = fmaxf(acc[10], acc[11]);
            float v6 = fmaxf(acc[12], acc[13]), v7 = fmaxf(acc[14], acc[15]);
            float v = fmaxf(fmaxf(fmaxf(v0, v1), fmaxf(v2, v3)),
                            fmaxf(fmaxf(v4, v5), fmaxf(v6, v7)));
            gm[mt] = fmaxf(v, __shfl_xor(v, 32, 64));   // both halves hold max
        }
        sel[g] = (l < 32) ? gm[0] : gm[1];  // lane l owns row m0 + l
    }

    float* dst = gmaxT + (size_t)(m0 + l) * NGRP + blockIdx.y * (PCH / GRP);
    #pragma unroll
    for (int q = 0; q < 4; ++q) {
        float4 st = {sel[4 * q], sel[4 * q + 1], sel[4 * q + 2], sel[4 * q + 3]};
        *(float4*)(dst + 4 * q) = st;
    }
}

// ---------------- Kernel C2: per-row pick + fused loss partial ----------
__global__ __launch_bounds__(256)
void k_pick(const float* __restrict__ gmaxT, const float* __restrict__ zn,
            const float* __restrict__ cn, const float* __restrict__ cnG,
            int* __restrict__ idx_i, float* __restrict__ idx_f,
            float* __restrict__ lossp) {
    int wv = threadIdx.x >> 6, l = threadIdx.x & 63;
    int m = blockIdx.x * 4 + wv;            // one wave per row

    float gv[4];
    #pragma unroll
    for (int b = 0; b < 4; ++b)
        gv[b] = gmaxT[(size_t)m * NGRP + b * 64 + l];
    float rm = fmaxf(fmaxf(gv[0], gv[1]), fmaxf(gv[2], gv[3]));
    #pragma unroll
    for (int o = 32; o; o >>= 1) rm = fmaxf(rm, __shfl_xor(rm, o, 64));
    float thr = rm - MARG;

    float zr[32];
    {
        const float4* zp = (const float4*)(zn + (size_t)m * C_DIM + (l >> 5) * 32);
        #pragma unroll
        for (int q = 0; q < 8; ++q) {
            float4 v = zp[q];
            zr[4 * q] = v.x; zr[4 * q + 1] = v.y;
            zr[4 * q + 2] = v.z; zr[4 * q + 3] = v.w;
        }
    }

    float bv = NEG_BIG; int bp = P_DIM;
    #pragma unroll
    for (int b = 0; b < 4; ++b) {           // ascending batches -> ascending groups
        unsigned long long mask = __ballot(gv[b] >= thr);
        while (mask) {
            int j = __ffsll((unsigned long long)mask) - 1;
            mask &= mask - 1;               // ascending j within batch
            int g = b * 64 + j;
            int p = g * GRP + (l & 31);
            const float* cg = cnG + (size_t)g * 2048;
            float a0 = 0.f, a1 = 0.f, a2 = 0.f, a3 = 0.f;
            #pragma unroll
            for (int q = 0; q < 8; ++q) {
                a0 = fmaf(cg[(4 * q + 0) * 64 + l], zr[4 * q + 0], a0);
                a1 = fmaf(cg[(4 * q + 1) * 64 + l], zr[4 * q + 1], a1);
                a2 = fmaf(cg[(4 * q + 2) * 64 + l], zr[4 * q + 2], a2);
                a3 = fmaf(cg[(4 * q + 3) * 64 + l], zr[4 * q + 3], a3);
            }
            float s = (a0 + a1) + (a2 + a3);
            s += __shfl_xor(s, 32, 64);     // combine halves: full dot in both lanes
            if (s > bv || (s == bv && p < bp)) { bv = s; bp = p; }
        }
    }
    #pragma unroll
    for (int o = 32; o; o >>= 1) {
        float ov = __shfl_xor(bv, o, 64);
        int   op = __shfl_xor(bp, o, 64);
        if (ov > bv || (ov == bv && op < bp)) { bv = ov; bp = op; }
    }
    if (l == 0) { idx_i[m] = bp; idx_f[m] = (float)bp; }

    // fused loss partial: sum (zn - cn[bp])^2 over the row (bp wave-uniform)
    {
        const float4* cp = (const float4*)(cn + (size_t)bp * C_DIM + (l >> 5) * 32);
        float d2 = 0.f;
        #pragma unroll
        for (int q = 0; q < 8; ++q) {
            float4 w = cp[q];
            float dx = zr[4 * q + 0] - w.x; d2 = fmaf(dx, dx, d2);
            float dy = zr[4 * q + 1] - w.y; d2 = fmaf(dy, dy, d2);
            float dz = zr[4 * q + 2] - w.z; d2 = fmaf(dz, dz, d2);
            float dw = zr[4 * q + 3] - w.w; d2 = fmaf(dw, dw, d2);
        }
        d2 += __shfl_xor(d2, 32, 64);
        if (l == 0) lossp[m] = d2;
    }
}

// ---------------- Kernel D (merged with loss-final): out + loss reduce ----------
// r22's proven body: readfirstlane row index -> scalar idx load -> SGPR-based
// cn addressing; compiler pipelines all 32 rows' scalar loads.
#define D_ROWS 128
#define D_BLKS (M_TOT / D_ROWS * (F_DIM / 64))      // 1536
__global__ void k_out(const int* __restrict__ idx, const float* __restrict__ cn,
                      const float* __restrict__ wT, float* __restrict__ out,
                      const float* __restrict__ lossp, float* __restrict__ loss_out) {
    __shared__ float sh[256];
    int bx = blockIdx.x;
    if (bx >= D_BLKS) {
        float s = 0.f;
        for (int i = threadIdx.x; i < M_TOT; i += 256) s += lossp[i];
        sh[threadIdx.x] = s;
        __syncthreads();
        for (int o = 128; o; o >>= 1) {
            if (threadIdx.x < o) sh[threadIdx.x] += sh[threadIdx.x + o];
            __syncthreads();
        }
        if (threadIdx.x == 0)
            loss_out[0] = 1.25f * sh[0] / (float)(M_TOT * C_DIM);
        return;
    }

    int wv = threadIdx.x >> 6, lane = threadIdx.x & 63;
    int f  = (bx >> 7) * 64 + lane;     // bx/128 in 0..11
    int m0 = (bx & 127) * D_ROWS + wv * 32;

    float wcol[64];
    #pragma unroll
    for (int c = 0; c < 64; ++c) wcol[c] = wT[(size_t)c * F_DIM + f];

    #pragma unroll 4
    for (int r = 0; r < 32; ++r) {
        int m = __builtin_amdgcn_readfirstlane(m0 + r);
        const float4* cp = (const float4*)(cn + (size_t)idx[m] * C_DIM);
        float a0 = 0.f, a1 = 0.f, a2 = 0.f, a3 = 0.f;
        #pragma unroll
        for (int j = 0; j < 16; ++j) {
            float4 cv = cp[j];
            a0 = fmaf(cv.x, wcol[4 * j + 0], a0);
            a1 = fmaf(cv.y, wcol[4 * j + 1], a1);
            a2 = fmaf(cv.z, wcol[4 * j + 2], a2);
            a3 = fmaf(cv.w, wcol[4 * j + 3], a3);
        }
        out[(size_t)m * F_DIM + f] = (a0 + a1) + (a2 + a3);
    }
}

extern "C" void kernel_launch(void* const* d_in, const int* in_sizes, int n_in,
                              void* d_out, int out_size, void* d_ws, size_t ws_size,
                              hipStream_t stream) {
    const float* z     = (const float*)d_in[0];
    const float* w_in  = (const float*)d_in[1];
    const float* w_out = (const float*)d_in[2];
    const float* cb    = (const float*)d_in[3];

    float* out    = (float*)d_out;
    float* lossO  = out + (size_t)M_TOT * F_DIM;
    float* idxO   = lossO + 1;
    // gmaxT (16.8 MB, [M_TOT][NGRP]) lives in the d_out 'out' region: written by
    // k_simmax, read by k_pick, then fully overwritten by k_out (stream-ordered).
    float* gmaxT  = out;

    float* ws    = (float*)d_ws;                          // total ~11.4 MB
    float* cn    = ws;                                    // 524288 f   (2 MB)
    float* zn    = cn + (size_t)P_DIM * C_DIM;            // 1048576 f  (4 MB)
    float* wT    = zn + (size_t)M_TOT * C_DIM;            // 49152 f
    float* lossp = wT + (size_t)C_DIM * F_DIM;            // 16384 f
    int*   idxi  = (int*)(lossp + M_TOT);                 // 16384 i
    float* cnG   = (float*)(idxi + M_TOT);                // 524288 f   (2 MB)
    ushort_t* zhF = (ushort_t*)(cnG + (size_t)P_DIM * C_DIM); // 1048576 us (2 MB)
    ushort_t* chF = zhF + (size_t)M_TOT * C_DIM;          // 524288 us  (1 MB)

    int projGrid = PROJ_BLKS + NGRP + F_DIM / 64;         // 512 + 256 + 12
    k_proj<<<projGrid, 256, 0, stream>>>(z, w_in, zn, zhF, cb, cn, chF, cnG, w_out, wT);

    dim3 gC(M_TOT / 256, NCH);
    k_simmax<<<gC, 256, 0, stream>>>(zhF, chF, gmaxT);
    k_pick<<<M_TOT / 4, 256, 0, stream>>>(gmaxT, zn, cn, cnG, idxi, idxO, lossp);

    k_out<<<D_BLKS + 1, 256, 0, stream>>>(idxi, cn, wT, out, lossp, lossO);
}